// Round 9
// baseline (209.265 us; speedup 1.0000x reference)
//
#include <hip/hip_runtime.h>
#include <hip/hip_bf16.h>

#define N_ROWS 20000
#define KNN 32
#define DIN 128
#define DOUT 128

// ---- kernel 0: pack transposed/fused weight layout ----
// WTp float layout: [d4][j][i] where d = d4*4+i, j in [0,256)
//   j <  128 : channel j of XA (wh[j][d]) ; j >= 128 : channel j-128 of XB (wh[j-128][128+d])
__global__ __launch_bounds__(256) void pack_wt(const float* __restrict__ wh,
                                               float* __restrict__ WTp) {
    int tid = blockIdx.x * 256 + threadIdx.x;  // 0..32767
    int i  = tid & 3;
    int j  = (tid >> 2) & 255;
    int d4 = tid >> 10;
    int d  = d4 * 4 + i;
    float v = (j < 128) ? wh[j * 256 + d] : wh[(j - 128) * 256 + 128 + d];
    WTp[tid] = v;
}

// ---- kernel 1: XA16[n][o] = bf16(x[n]·wh[o,:128]) ; XBp[n][o] = x[n]·wh[o,128:] + bh[o]
// 16-row tiles (1250 blocks -> 4.9 waves/SIMD), 256 threads:
// tx = t&63 (channel), ty = t>>6, 4 rows/thread
__global__ __launch_bounds__(256) void gemm_xaxb(const float* __restrict__ x,
                                                 const float* __restrict__ WTp,
                                                 const float* __restrict__ bh,
                                                 __hip_bfloat16* __restrict__ XA16,
                                                 float* __restrict__ XBp) {
    __shared__ float xs[16][128];   // 8 KB
    const int t = threadIdx.x;
    const int row0 = blockIdx.x * 16;   // 1250*16 == 20000 exactly

    #pragma unroll
    for (int i = 0; i < 2; ++i) {
        int idx = t + i * 256;          // float4 slot in [0,512)
        int r = idx >> 5, c4 = idx & 31;
        ((float4*)xs[r])[c4] = ((const float4*)(x + (size_t)(row0 + r) * DIN))[c4];
    }
    __syncthreads();

    const int tx = t & 63;
    const int ty = t >> 6;
    const int r0 = ty * 4;
    float acc[4][4];
    #pragma unroll
    for (int r = 0; r < 4; ++r)
        #pragma unroll
        for (int c = 0; c < 4; ++c) acc[r][c] = 0.f;

    const float4* W4 = (const float4*)WTp;
    for (int d4 = 0; d4 < 32; ++d4) {
        float4 w0 = W4[d4 * 256 + tx];         // XA, channel tx
        float4 w1 = W4[d4 * 256 + 64 + tx];    // XA, channel tx+64
        float4 w2 = W4[d4 * 256 + 128 + tx];   // XB, channel tx
        float4 w3 = W4[d4 * 256 + 192 + tx];   // XB, channel tx+64
        #pragma unroll
        for (int r = 0; r < 4; ++r) {
            float4 xv = ((const float4*)xs[r0 + r])[d4];  // wave-uniform broadcast
            acc[r][0] += xv.x * w0.x + xv.y * w0.y + xv.z * w0.z + xv.w * w0.w;
            acc[r][1] += xv.x * w1.x + xv.y * w1.y + xv.z * w1.z + xv.w * w1.w;
            acc[r][2] += xv.x * w2.x + xv.y * w2.y + xv.z * w2.z + xv.w * w2.w;
            acc[r][3] += xv.x * w3.x + xv.y * w3.y + xv.z * w3.z + xv.w * w3.w;
        }
    }

    float bh0 = bh[tx], bh1 = bh[64 + tx];
    #pragma unroll
    for (int r = 0; r < 4; ++r) {
        size_t gr = row0 + r0 + r;
        XA16[gr * DOUT + tx]       = __float2bfloat16(acc[r][0]);
        XA16[gr * DOUT + 64 + tx]  = __float2bfloat16(acc[r][1]);
        XBp [gr * DOUT + tx]       = acc[r][2] + bh0;
        XBp [gr * DOUT + 64 + tx]  = acc[r][3] + bh1;
    }
}

// ---- kernel 2: one wave (64 threads) per n. idx/d broadcast via readlane ->
// SGPR gather base (scalar addressing, 1 VGPR per in-flight load, all 32 pipelined).
// Position partials: 3 DPP shfl_xor in-loop -> 8 partials/k in 1.2 KB LDS.
__global__ __launch_bounds__(64, 8) void fused_main(const float* __restrict__ dists,
                                                    const int*  __restrict__ argm,
                                                    const float* __restrict__ w1d,
                                                    const float* __restrict__ b1d,
                                                    const float* __restrict__ w2d,
                                                    const float* __restrict__ b2d,
                                                    const float* __restrict__ wp,
                                                    const float* __restrict__ bp,
                                                    const __hip_bfloat16* __restrict__ XA16,
                                                    const float* __restrict__ XBp,
                                                    float* __restrict__ out_pos,
                                                    float* __restrict__ out_struct) {
    const int n    = blockIdx.x;
    const int lane = threadIdx.x;                // 0..63

    __shared__ float pos_p[KNN][9];              // stride 9: 9k+g mod 32 bijective in k

    // ---- distance MLP: k = lane&31, sub = lane>>5 handles 64 channels; 1 shfl_xor(32)
    const int k = lane & 31, sub = lane >> 5;
    float s = dists[(size_t)n * KNN + k];
    float a = 0.f;
    {
        const float4* W1 = (const float4*)(w1d + sub * 64);
        const float4* B1 = (const float4*)(b1d + sub * 64);
        const float4* W2 = (const float4*)(w2d + sub * 64);
        #pragma unroll
        for (int o4 = 0; o4 < 16; ++o4) {
            float4 w1 = W1[o4], b1 = B1[o4], w2 = W2[o4];
            a += fmaxf(fmaf(s, w1.x, b1.x), 0.f) * w2.x;
            a += fmaxf(fmaf(s, w1.y, b1.y), 0.f) * w2.y;
            a += fmaxf(fmaf(s, w1.z, b1.z), 0.f) * w2.z;
            a += fmaxf(fmaf(s, w1.w, b1.w), 0.f) * w2.w;
        }
    }
    a += __shfl_xor(a, 32);
    const float dval = a + b2d[0];               // lanes k and k+32 both hold d_k
    const int   idxv = argm[(size_t)n * KNN + k];// lanes k and k+32 hold idx_k

    // per-lane channel pair c = {2*lane, 2*lane+1}
    const float2 base = *(const float2*)(XBp + (size_t)n * DOUT + lane * 2);
    const float2 wpv  = *(const float2*)(wp + lane * 2);

    const unsigned* xa32 = (const unsigned*)XA16;   // row = 64 uints = 128 bf16
    float s0 = 0.f, s1 = 0.f;
    #pragma unroll
    for (int kk = 0; kk < KNN; ++kk) {
        int   m  = __builtin_amdgcn_readlane(idxv, kk);   // SGPR, uniform
        float dk = __int_as_float(__builtin_amdgcn_readlane(__float_as_int(dval), kk));
        unsigned u = xa32[(size_t)m * 64 + lane];         // s[base] + lane*4
        float xa0 = __uint_as_float(u << 16);             // low bf16
        float xa1 = __uint_as_float(u & 0xFFFF0000u);     // high bf16
        float h0 = fmaxf(fmaf(dk, xa0, base.x), 0.f);
        float h1 = fmaxf(fmaf(dk, xa1, base.y), 0.f);
        s0 += h0; s1 += h1;
        float pv = fmaf(h1, wpv.y, h0 * wpv.x);
        pv += __shfl_xor(pv, 1);                          // DPP adds
        pv += __shfl_xor(pv, 2);
        pv += __shfl_xor(pv, 4);
        if ((lane & 7) == 0) pos_p[kk][lane >> 3] = pv;   // 8 banks, conflict-free
    }
    *(float2*)(out_struct + (size_t)n * DOUT + lane * 2) =
        make_float2(s0 * (1.f / KNN), s1 * (1.f / KNN));
    __syncthreads();   // single-wave block: cheap; orders LDS writes->reads

    if (lane < KNN) {
        const float* row = pos_p[lane];                   // banks 9*lane+g: bijective
        float p = ((row[0] + row[1]) + (row[2] + row[3]))
                + ((row[4] + row[5]) + (row[6] + row[7]));
        out_pos[(size_t)n * KNN + lane] = p + bp[0];
    }
}

extern "C" void kernel_launch(void* const* d_in, const int* in_sizes, int n_in,
                              void* d_out, int out_size, void* d_ws, size_t ws_size,
                              hipStream_t stream) {
    const float* data_x = (const float*)d_in[0];
    const float* dists  = (const float*)d_in[1];
    const int*   argm   = (const int*)d_in[2];
    const float* w1d    = (const float*)d_in[3];
    const float* b1d    = (const float*)d_in[4];
    const float* w2d    = (const float*)d_in[5];
    const float* b2d    = (const float*)d_in[6];
    const float* wh     = (const float*)d_in[7];
    const float* bh     = (const float*)d_in[8];
    const float* wp     = (const float*)d_in[9];
    const float* bp     = (const float*)d_in[10];

    float* out_pos    = (float*)d_out;                       // [N,K]
    float* out_struct = out_pos + (size_t)N_ROWS * KNN;      // [N,DOUT]

    float*          XBp  = (float*)d_ws;                                  // [N,128] f32
    __hip_bfloat16* XA16 = (__hip_bfloat16*)(XBp + (size_t)N_ROWS * DOUT);// [N,128] bf16
    float*          WTp  = (float*)((char*)XA16 + (size_t)N_ROWS * DOUT * 2); // 32768 f32

    pack_wt<<<128, 256, 0, stream>>>(wh, WTp);
    gemm_xaxb<<<N_ROWS / 16, 256, 0, stream>>>(data_x, WTp, bh, XA16, XBp);
    fused_main<<<N_ROWS, 64, 0, stream>>>(dists, argm, w1d, b1d, w2d, b2d,
                                          wp, bp, XA16, XBp, out_pos, out_struct);
}

// Round 10
// 181.550 us; speedup vs baseline: 1.1527x; 1.1527x over previous
//
#include <hip/hip_runtime.h>
#include <hip/hip_bf16.h>

#define N_ROWS 20000
#define KNN 32
#define DIN 128
#define DOUT 128

// ---- kernel 0: pack transposed/fused weight layout ----
// WTp float layout: [d4][j][i] where d = d4*4+i, j in [0,256)
//   j <  128 : channel j of XA (wh[j][d]) ; j >= 128 : channel j-128 of XB (wh[j-128][128+d])
__global__ __launch_bounds__(256) void pack_wt(const float* __restrict__ wh,
                                               float* __restrict__ WTp) {
    int tid = blockIdx.x * 256 + threadIdx.x;  // 0..32767
    int i  = tid & 3;
    int j  = (tid >> 2) & 255;
    int d4 = tid >> 10;
    int d  = d4 * 4 + i;
    float v = (j < 128) ? wh[j * 256 + d] : wh[(j - 128) * 256 + 128 + d];
    WTp[tid] = v;
}

// ---- kernel 1: XA16[n][o] = bf16(x[n]·wh[o,:128]) ; XBp[n][o] = x[n]·wh[o,128:] + bh[o]
// 16-row tiles (1250 blocks), 256 threads: tx = t&63 (channel), ty = t>>6, 4 rows/thread
__global__ __launch_bounds__(256) void gemm_xaxb(const float* __restrict__ x,
                                                 const float* __restrict__ WTp,
                                                 const float* __restrict__ bh,
                                                 __hip_bfloat16* __restrict__ XA16,
                                                 float* __restrict__ XBp) {
    __shared__ float xs[16][128];   // 8 KB
    const int t = threadIdx.x;
    const int row0 = blockIdx.x * 16;   // 1250*16 == 20000 exactly

    #pragma unroll
    for (int i = 0; i < 2; ++i) {
        int idx = t + i * 256;          // float4 slot in [0,512)
        int r = idx >> 5, c4 = idx & 31;
        ((float4*)xs[r])[c4] = ((const float4*)(x + (size_t)(row0 + r) * DIN))[c4];
    }
    __syncthreads();

    const int tx = t & 63;
    const int ty = t >> 6;
    const int r0 = ty * 4;
    float acc[4][4];
    #pragma unroll
    for (int r = 0; r < 4; ++r)
        #pragma unroll
        for (int c = 0; c < 4; ++c) acc[r][c] = 0.f;

    const float4* W4 = (const float4*)WTp;
    for (int d4 = 0; d4 < 32; ++d4) {
        float4 w0 = W4[d4 * 256 + tx];         // XA, channel tx
        float4 w1 = W4[d4 * 256 + 64 + tx];    // XA, channel tx+64
        float4 w2 = W4[d4 * 256 + 128 + tx];   // XB, channel tx
        float4 w3 = W4[d4 * 256 + 192 + tx];   // XB, channel tx+64
        #pragma unroll
        for (int r = 0; r < 4; ++r) {
            float4 xv = ((const float4*)xs[r0 + r])[d4];  // wave-uniform broadcast
            acc[r][0] += xv.x * w0.x + xv.y * w0.y + xv.z * w0.z + xv.w * w0.w;
            acc[r][1] += xv.x * w1.x + xv.y * w1.y + xv.z * w1.z + xv.w * w1.w;
            acc[r][2] += xv.x * w2.x + xv.y * w2.y + xv.z * w2.z + xv.w * w2.w;
            acc[r][3] += xv.x * w3.x + xv.y * w3.y + xv.z * w3.z + xv.w * w3.w;
        }
    }

    float bh0 = bh[tx], bh1 = bh[64 + tx];
    #pragma unroll
    for (int r = 0; r < 4; ++r) {
        size_t gr = row0 + r0 + r;
        XA16[gr * DOUT + tx]       = __float2bfloat16(acc[r][0]);
        XA16[gr * DOUT + 64 + tx]  = __float2bfloat16(acc[r][1]);
        XBp [gr * DOUT + tx]       = acc[r][2] + bh0;
        XBp [gr * DOUT + 64 + tx]  = acc[r][3] + bh1;
    }
}

// ---- kernel 2: one wave (64 threads) per n. idx/d broadcast via readlane ->
// SGPR gather base (scalar addressing). NO launch-bounds reg cap: R9's
// __launch_bounds__(64,8) forced 64-VGPR budget -> scratch spills
// (WRITE_SIZE 12.5->148 MB). Let the compiler keep all 32 gathers in flight.
// Position partials: 3 DPP shfl_xor in-loop -> 8 partials/k in 1.2 KB LDS.
__global__ __launch_bounds__(64) void fused_main(const float* __restrict__ dists,
                                                 const int*  __restrict__ argm,
                                                 const float* __restrict__ w1d,
                                                 const float* __restrict__ b1d,
                                                 const float* __restrict__ w2d,
                                                 const float* __restrict__ b2d,
                                                 const float* __restrict__ wp,
                                                 const float* __restrict__ bp,
                                                 const __hip_bfloat16* __restrict__ XA16,
                                                 const float* __restrict__ XBp,
                                                 float* __restrict__ out_pos,
                                                 float* __restrict__ out_struct) {
    const int n    = blockIdx.x;
    const int lane = threadIdx.x;                // 0..63

    __shared__ float pos_p[KNN][9];              // stride 9: 9k+g mod 32 bijective in k

    // ---- distance MLP: k = lane&31, sub = lane>>5 handles 64 channels; 1 shfl_xor(32)
    const int k = lane & 31, sub = lane >> 5;
    float s = dists[(size_t)n * KNN + k];
    float a = 0.f;
    {
        const float4* W1 = (const float4*)(w1d + sub * 64);
        const float4* B1 = (const float4*)(b1d + sub * 64);
        const float4* W2 = (const float4*)(w2d + sub * 64);
        #pragma unroll
        for (int o4 = 0; o4 < 16; ++o4) {
            float4 w1 = W1[o4], b1 = B1[o4], w2 = W2[o4];
            a += fmaxf(fmaf(s, w1.x, b1.x), 0.f) * w2.x;
            a += fmaxf(fmaf(s, w1.y, b1.y), 0.f) * w2.y;
            a += fmaxf(fmaf(s, w1.z, b1.z), 0.f) * w2.z;
            a += fmaxf(fmaf(s, w1.w, b1.w), 0.f) * w2.w;
        }
    }
    a += __shfl_xor(a, 32);
    const float dval = a + b2d[0];               // lanes k and k+32 both hold d_k
    const int   idxv = argm[(size_t)n * KNN + k];// lanes k and k+32 hold idx_k

    // per-lane channel pair c = {2*lane, 2*lane+1}
    const float2 base = *(const float2*)(XBp + (size_t)n * DOUT + lane * 2);
    const float2 wpv  = *(const float2*)(wp + lane * 2);

    const unsigned* xa32 = (const unsigned*)XA16;   // row = 64 uints = 128 bf16
    float s0 = 0.f, s1 = 0.f;
    #pragma unroll
    for (int kk = 0; kk < KNN; ++kk) {
        int   m  = __builtin_amdgcn_readlane(idxv, kk);   // SGPR, uniform
        float dk = __int_as_float(__builtin_amdgcn_readlane(__float_as_int(dval), kk));
        unsigned u = xa32[(size_t)m * 64 + lane];         // s[base] + lane*4
        float xa0 = __uint_as_float(u << 16);             // low bf16
        float xa1 = __uint_as_float(u & 0xFFFF0000u);     // high bf16
        float h0 = fmaxf(fmaf(dk, xa0, base.x), 0.f);
        float h1 = fmaxf(fmaf(dk, xa1, base.y), 0.f);
        s0 += h0; s1 += h1;
        float pv = fmaf(h1, wpv.y, h0 * wpv.x);
        pv += __shfl_xor(pv, 1);                          // DPP adds
        pv += __shfl_xor(pv, 2);
        pv += __shfl_xor(pv, 4);
        if ((lane & 7) == 0) pos_p[kk][lane >> 3] = pv;   // 8 banks, conflict-free
    }
    *(float2*)(out_struct + (size_t)n * DOUT + lane * 2) =
        make_float2(s0 * (1.f / KNN), s1 * (1.f / KNN));
    __syncthreads();   // single-wave block: cheap; orders LDS writes->reads

    if (lane < KNN) {
        const float* row = pos_p[lane];                   // banks 9*lane+j: bijective
        float p = ((row[0] + row[1]) + (row[2] + row[3]))
                + ((row[4] + row[5]) + (row[6] + row[7]));
        out_pos[(size_t)n * KNN + lane] = p + bp[0];
    }
}

extern "C" void kernel_launch(void* const* d_in, const int* in_sizes, int n_in,
                              void* d_out, int out_size, void* d_ws, size_t ws_size,
                              hipStream_t stream) {
    const float* data_x = (const float*)d_in[0];
    const float* dists  = (const float*)d_in[1];
    const int*   argm   = (const int*)d_in[2];
    const float* w1d    = (const float*)d_in[3];
    const float* b1d    = (const float*)d_in[4];
    const float* w2d    = (const float*)d_in[5];
    const float* b2d    = (const float*)d_in[6];
    const float* wh     = (const float*)d_in[7];
    const float* bh     = (const float*)d_in[8];
    const float* wp     = (const float*)d_in[9];
    const float* bp     = (const float*)d_in[10];

    float* out_pos    = (float*)d_out;                       // [N,K]
    float* out_struct = out_pos + (size_t)N_ROWS * KNN;      // [N,DOUT]

    float*          XBp  = (float*)d_ws;                                  // [N,128] f32
    __hip_bfloat16* XA16 = (__hip_bfloat16*)(XBp + (size_t)N_ROWS * DOUT);// [N,128] bf16
    float*          WTp  = (float*)((char*)XA16 + (size_t)N_ROWS * DOUT * 2); // 32768 f32

    pack_wt<<<128, 256, 0, stream>>>(wh, WTp);
    gemm_xaxb<<<N_ROWS / 16, 256, 0, stream>>>(data_x, WTp, bh, XA16, XBp);
    fused_main<<<N_ROWS, 64, 0, stream>>>(dists, argm, w1d, b1d, w2d, b2d,
                                          wp, bp, XA16, XBp, out_pos, out_struct);
}